// Round 9
// baseline (1118.140 us; speedup 1.0000x reference)
//
#include <hip/hip_runtime.h>
#include <hip/hip_bf16.h>

// ---------- types / helpers ----------
typedef unsigned short u16;
typedef __bf16  bf16x8 __attribute__((ext_vector_type(8)));
typedef float   f32x4  __attribute__((ext_vector_type(4)));
typedef float   f32x2  __attribute__((ext_vector_type(2)));
typedef unsigned int   u32x4 __attribute__((ext_vector_type(4)));
typedef unsigned short u16x4 __attribute__((ext_vector_type(4)));

union FragU { bf16x8 v; u16 u[8]; u32x4 q; };

__device__ __forceinline__ float b2f(u16 u) {
    unsigned int x = ((unsigned int)u) << 16;
    return __builtin_bit_cast(float, x);
}
__device__ __forceinline__ u16 f2b(float f) {
    unsigned int x = __builtin_bit_cast(unsigned int, f);
    unsigned int r = (x + 0x7fffu + ((x >> 16) & 1u)) >> 16;
    return (u16)r;
}
__device__ __forceinline__ float rcp_(float x) { return __builtin_amdgcn_rcpf(x); }
__device__ __forceinline__ float sigm_(float x) { return rcp_(1.0f + __expf(-x)); }
__device__ __forceinline__ float tanh_(float x) {
    float e = __expf(2.0f * x);
    return 1.0f - 2.0f * rcp_(e + 1.0f);
}
__device__ __forceinline__ bf16x8 load_afrag(const u16* s) {
    FragU f; f.q = *(const u32x4*)s; return f.v;
}
__device__ __forceinline__ f32x4 mfma16(bf16x8 a, bf16x8 b, f32x4 c) {
    return __builtin_amdgcn_mfma_f32_16x16x32_bf16(a, b, c, 0, 0, 0);
}
// split helper: hi bf16 + residual lo bf16
__device__ __forceinline__ void split2(float f, u16& hi, u16& lo) {
    hi = f2b(f); lo = f2b(f - b2f(hi));
}

// ---------------------------------------------------------------------------
// Split-bf16 GEMM body (effective-fp32): out = A @ W + bias (3 MFMAs/product)
// MODE 0: vocab-enc  A[256,128] = src_emb,      out xpv fp32 [256,192]
// MODE 1: vocab-dec  A[256,64]  = out_W^T * 8,  out xpv fp32 [256,192]
// MODE 2: enc_proj   A = encF fp32, K=64,N=64,
//         out bf16 encpT[b][a][s] = (acc+be)*2   (coalesced in s)
// MODE 3: logits     A = hid hi/lo planes, K=64,N=256, out fp32 d_out
// 256 thr, 64 rows; wave w covers cols [w*N/4,(w+1)*N/4)
// ---------------------------------------------------------------------------
template<int MODE, int K, int N>
__device__ __forceinline__ void gemm_body(
    const float* __restrict__ srcf, const u16* __restrict__ sh,
    const u16* __restrict__ sl, const float* __restrict__ W,
    const float* __restrict__ bias, float* __restrict__ outf,
    u16* __restrict__ outh, int rbase)
{
    constexpr int KP = K + 8;
    constexpr int LK = (K == 128) ? 7 : 6;
    __shared__ __attribute__((aligned(16))) u16 Ash[64 * KP];
    __shared__ __attribute__((aligned(16))) u16 Asl[64 * KP];

    const int tid  = threadIdx.x;
    const int lane = tid & 63, w = tid >> 6;
    const int q = lane >> 4, ln = lane & 15;

    // ---- stage A rows into LDS hi/lo ----
    for (int i = tid; i < 64 * K; i += 256) {
        int r = i >> LK, c = i & (K - 1);
        int rg = rbase + r;
        float f;
        if constexpr (MODE == 0)      f = srcf[rg * K + c];
        else if constexpr (MODE == 1) f = srcf[c * 256 + rg] * 8.0f;
        else if constexpr (MODE == 2) f = srcf[rg * 64 + c];
        else                          f = b2f(sh[rg * 64 + c]) + b2f(sl[rg * 64 + c]);
        u16 hi, lo; split2(f, hi, lo);
        Ash[r * KP + c] = hi; Asl[r * KP + c] = lo;
    }

    // ---- B fragments hi/lo in registers ----
    constexpr int NT  = N / 64;
    constexpr int NKF = K / 32;
    FragU bfh[NT][NKF], bfl[NT][NKF];
    float bv[NT];
    const int cw = w * (N >> 2);
#pragma unroll
    for (int tl = 0; tl < NT; ++tl) {
        int col = cw + tl * 16 + ln;
#pragma unroll
        for (int kf = 0; kf < NKF; ++kf)
#pragma unroll
            for (int j = 0; j < 8; ++j) {
                float f = W[(kf * 32 + q * 8 + j) * N + col];
                split2(f, bfh[tl][kf].u[j], bfl[tl][kf].u[j]);
            }
        bv[tl] = bias[col];
    }
    __syncthreads();

#pragma unroll
    for (int r = 0; r < 4; ++r) {
        bf16x8 afh[NKF], afl[NKF];
#pragma unroll
        for (int kf = 0; kf < NKF; ++kf) {
            afh[kf] = load_afrag(&Ash[(r * 16 + ln) * KP + kf * 32 + q * 8]);
            afl[kf] = load_afrag(&Asl[(r * 16 + ln) * KP + kf * 32 + q * 8]);
        }
#pragma unroll
        for (int tl = 0; tl < NT; ++tl) {
            f32x4 acc = {0.f, 0.f, 0.f, 0.f};
#pragma unroll
            for (int kf = 0; kf < NKF; ++kf) {
                acc = mfma16(afl[kf], bfh[tl][kf].v, acc);
                acc = mfma16(afh[kf], bfl[tl][kf].v, acc);
                acc = mfma16(afh[kf], bfh[tl][kf].v, acc);
            }
            const int col = cw + tl * 16 + ln;
#pragma unroll
            for (int i = 0; i < 4; ++i) {
                int rowg = rbase + r * 16 + q * 4 + i;
                float val = acc[i] + bv[tl];
                if constexpr (MODE == 2) {
                    int b = rowg >> 5, s2 = rowg & 31;
                    outh[(b * 64 + col) * 32 + s2] = f2b(val * 2.0f);
                } else if constexpr (MODE == 3) {
                    outf[rowg * N + col] = val;
                } else {
                    outf[rowg * 192 + col] = val;
                }
            }
        }
    }
}

template<int MODE, int K, int N>
__global__ __launch_bounds__(256, (MODE >= 2) ? 2 : 1) void gemm_hl(
    const float* __restrict__ srcf, const u16* __restrict__ sh,
    const u16* __restrict__ sl, const float* __restrict__ W,
    const float* __restrict__ bias, float* __restrict__ outf,
    u16* __restrict__ outh)
{
    gemm_body<MODE, K, N>(srcf, sh, sl, W, bias, outf, outh,
                          (int)blockIdx.x * 64);
}

// All three tiny vocab-table GEMMs in ONE launch (12 blocks).
__global__ __launch_bounds__(256, 1) void xpv_all(
    const float* __restrict__ src_emb,
    const float* __restrict__ Wf, const float* __restrict__ bf, float* __restrict__ xf,
    const float* __restrict__ Wb, const float* __restrict__ bb, float* __restrict__ xb,
    const float* __restrict__ outW, const float* __restrict__ dW,
    const float* __restrict__ db, float* __restrict__ xd)
{
    const int b = blockIdx.x;
    if (b < 4)
        gemm_body<0, 128, 192>(src_emb, nullptr, nullptr, Wf, bf, xf, nullptr, b * 64);
    else if (b < 8)
        gemm_body<0, 128, 192>(src_emb, nullptr, nullptr, Wb, bb, xb, nullptr, (b - 4) * 64);
    else
        gemm_body<1, 64, 192>(outW, nullptr, nullptr, dW, db, xd, nullptr, (b - 8) * 64);
}

// ---------------------------------------------------------------------------
// Fused bidirectional encoder GRU (split-bf16), 8 rows/block, 1024 blocks.
// Both directions atomicAdd their h into encF fp32 (zeroed beforehand);
// fp32 add of 2 addends is commutative -> dispatch-order independent.
// ---------------------------------------------------------------------------
__global__ __launch_bounds__(256, 2) void enc8(
    const int* __restrict__ src_ids, const float* __restrict__ xf,
    const float* __restrict__ xb,
    const float* __restrict__ Uf_, const float* __restrict__ bf_,
    const float* __restrict__ Ub_, const float* __restrict__ bb_,
    float* __restrict__ encF)
{
    __shared__ __attribute__((aligned(16))) u16 hsh[16 * 72];
    __shared__ __attribute__((aligned(16))) u16 hsl[16 * 72];
    const int tid  = threadIdx.x;
    const int lane = tid & 63, w = tid >> 6;
    const int q = lane >> 4, ln = lane & 15;
    const int dir = (int)(blockIdx.x >> 9);
    const int b0  = (int)(blockIdx.x & 511) * 8;
    const float* xpv = dir ? xb  : xf;
    const float* U   = dir ? Ub_ : Uf_;
    const float* b_  = dir ? bb_ : bf_;
    const int jw = w * 16;
    const bool rowok = (q < 2);

    for (int i = tid; i < 16 * 64; i += 256) {
        int r = i >> 6, c = i & 63;
        hsh[r * 72 + c] = 0; hsl[r * 72 + c] = 0;
    }
    FragU ufh[3][2], ufl[3][2];
    float b1[3];
#pragma unroll
    for (int g = 0; g < 3; ++g) {
        int col = g * 64 + jw + ln;
#pragma unroll
        for (int kf = 0; kf < 2; ++kf)
#pragma unroll
            for (int j = 0; j < 8; ++j) {
                float f = U[(kf * 32 + q * 8 + j) * 192 + col];
                split2(f, ufh[g][kf].u[j], ufl[g][kf].u[j]);
            }
        b1[g] = b_[192 + col];
    }
    float hp[4] = {0, 0, 0, 0};

    float xg[3][4];
    {
        const int s0 = dir ? 31 : 0;
#pragma unroll
        for (int i = 0; i < 4; ++i) {
            int rowv = b0 + ((q * 4 + i) & 7);
            int id = src_ids[rowv * 32 + s0];
#pragma unroll
            for (int g = 0; g < 3; ++g) xg[g][i] = xpv[id * 192 + g * 64 + jw + ln];
        }
    }
    __syncthreads();

    for (int step = 0; step < 32; ++step) {
        const int s = dir ? (31 - step) : step;
        float xgn[3][4];
        {
            int sn = dir ? (step >= 31 ? 0 : 30 - step) : (step >= 31 ? 31 : step + 1);
#pragma unroll
            for (int i = 0; i < 4; ++i) {
                int rowv = b0 + ((q * 4 + i) & 7);
                int id = src_ids[rowv * 32 + sn];
#pragma unroll
                for (int g = 0; g < 3; ++g) xgn[g][i] = xpv[id * 192 + g * 64 + jw + ln];
            }
        }
        bf16x8 a0h = load_afrag(&hsh[ln * 72 + q * 8]);
        bf16x8 a1h = load_afrag(&hsh[ln * 72 + 32 + q * 8]);
        bf16x8 a0l = load_afrag(&hsl[ln * 72 + q * 8]);
        bf16x8 a1l = load_afrag(&hsl[ln * 72 + 32 + q * 8]);
        f32x4 acc[3];
#pragma unroll
        for (int g = 0; g < 3; ++g) {
            f32x4 a = {0.f, 0.f, 0.f, 0.f};
            a = mfma16(a0l, ufh[g][0].v, a);
            a = mfma16(a0h, ufl[g][0].v, a);
            a = mfma16(a0h, ufh[g][0].v, a);
            a = mfma16(a1l, ufh[g][1].v, a);
            a = mfma16(a1h, ufl[g][1].v, a);
            a = mfma16(a1h, ufh[g][1].v, a);
            acc[g] = a;
        }
        float nh[4];
#pragma unroll
        for (int i = 0; i < 4; ++i) {
            const int rowg = b0 + q * 4 + i;
            float zz = sigm_(xg[0][i] + acc[0][i] + b1[0]);
            float rr = sigm_(xg[1][i] + acc[1][i] + b1[1]);
            float nn = tanh_(xg[2][i] + rr * (acc[2][i] + b1[2]));
            nh[i] = zz * hp[i] + (1.0f - zz) * nn;  hp[i] = nh[i];
            if (rowok) {
                const int gidx = (rowg * 32 + s) * 64 + jw + ln;
                atomicAdd(&encF[gidx], nh[i]);
            }
        }
        __syncthreads();
        if (rowok) {
#pragma unroll
            for (int i = 0; i < 4; ++i) {
                u16 hi, lo; split2(nh[i], hi, lo);
                hsh[(q * 4 + i) * 72 + jw + ln] = hi;
                hsl[(q * 4 + i) * 72 + jw + ln] = lo;
            }
        }
        __syncthreads();
#pragma unroll
        for (int g = 0; g < 3; ++g)
#pragma unroll
            for (int i = 0; i < 4; ++i) xg[g][i] = xgn[g][i];
    }
}

// ---------------------------------------------------------------------------
// Decoder: per-wave independent 4-row GRU machines — ZERO barriers in the
// t-loop. Rationale: R1 (4 waves/CU) == R8 (8 waves/CU) == ~310 µs proved
// the limiter is the barrier-locked serial chain, not occupancy. Each wave
// owns 4 batch rows and computes ALL columns itself (MFMA rows 4..15 are
// zero-padded via conditional-zero A-frags). Weight fragments staged ONCE
// into LDS (112 KiB, 1 KiB conflict-free per frag read). Wave-private LDS
// scratch needs only intra-wave ordering (compiler lgkmcnt) — no barrier.
// 256 blocks x 256 thr (4 waves x 4 rows = 16 rows) = one full round.
// (256,1): ~240 VGPR, no spill, 1 wave/SIMD (waves independent -> OK).
// ---------------------------------------------------------------------------
__global__ __launch_bounds__(256, 1) void dec_kernel(
    const int* __restrict__ tgt_ids, const float* __restrict__ xpvd,
    const float* __restrict__ encF, const u16* __restrict__ encpT,
    const float* __restrict__ dec_U, const float* __restrict__ dec_W,
    const float* __restrict__ dec_b,
    const float* __restrict__ Wd, const float* __restrict__ bd,
    const float* __restrict__ v_, const float* __restrict__ bv_,
    u16* __restrict__ hid_hi, u16* __restrict__ hid_lo)
{
    // weight fragment planes: wd_hi[0,4096) wd_lo[4096,8192)
    // u_hi[8192,20480) u_lo[20480,32768) wc_hi[32768,45056) wc_lo[45056,57344)
    __shared__ __attribute__((aligned(16))) u16 wlds[57344];      // 112 KiB
    __shared__ __attribute__((aligned(16))) u16 hqp[4][2][4][64]; // h hi/lo
    __shared__ __attribute__((aligned(16))) u16 cxp[4][2][4][64]; // ctx hi/lo
    __shared__ __attribute__((aligned(16))) float dpl_l[4][4][64];
    __shared__ float wl_l[4][4][32];
    __shared__ float vl[64];
    const int tid  = threadIdx.x;
    const int w = tid >> 6, lane = tid & 63;
    const int q = lane >> 4, ln = lane & 15;
    const int brow0 = (int)blockIdx.x * 16 + w * 4;

    // ---- stage weight fragments into LDS (block-cooperative, once) ----
    for (int idx = tid; idx < 4096; idx += 256) {
        int j = idx & 7, l2 = (idx >> 3) & 63, kf = (idx >> 9) & 1, tl = idx >> 10;
        int k = kf * 32 + (l2 >> 4) * 8 + j, col = tl * 16 + (l2 & 15);
        u16 hi, lo; split2(Wd[k * 64 + col], hi, lo);
        wlds[(tl * 2 + kf) * 512 + l2 * 8 + j] = hi;
        wlds[4096 + (tl * 2 + kf) * 512 + l2 * 8 + j] = lo;
    }
    for (int idx = tid; idx < 12288; idx += 256) {
        int j = idx & 7, l2 = (idx >> 3) & 63, kf = (idx >> 9) & 1, ct = idx >> 10;
        int k = kf * 32 + (l2 >> 4) * 8 + j, colg = ct * 16 + (l2 & 15);
        u16 hi, lo; split2(dec_U[k * 192 + colg], hi, lo);
        wlds[8192  + (ct * 2 + kf) * 512 + l2 * 8 + j] = hi;
        wlds[20480 + (ct * 2 + kf) * 512 + l2 * 8 + j] = lo;
        split2(dec_W[(64 + k) * 192 + colg], hi, lo);
        wlds[32768 + (ct * 2 + kf) * 512 + l2 * 8 + j] = hi;
        wlds[45056 + (ct * 2 + kf) * 512 + l2 * 8 + j] = lo;
    }
    if (tid < 64) vl[tid] = v_[tid];

    // per-lane constants (valid for lane&15; used under lane<16 guard)
    float bdv[4], b13[3][4];
#pragma unroll
    for (int tl = 0; tl < 4; ++tl) {
        bdv[tl] = bd[tl * 16 + (lane & 15)];
#pragma unroll
        for (int g = 0; g < 3; ++g)
            b13[g][tl] = dec_b[192 + g * 64 + tl * 16 + (lane & 15)];
    }

    // h0 = encoded[:,0]: lanes<16 own (col=tl*16+lane, rows i=0..3)
    float hp[4][4];
    if (lane < 16) {
#pragma unroll
        for (int tl = 0; tl < 4; ++tl)
#pragma unroll
            for (int i = 0; i < 4; ++i) {
                int col = tl * 16 + lane;
                float h0 = encF[((size_t)(brow0 + i) * 32) * 64 + col];
                hp[tl][i] = h0;
                u16 hi, lo; split2(h0, hi, lo);
                hqp[w][0][i][col] = hi; hqp[w][1][i][col] = lo;
            }
    }
    __syncthreads();   // weights + vl + initial h ready (the ONLY barrier)

    float SVB = bv_[0];
#pragma unroll
    for (int a = 0; a < 64; ++a) SVB += vl[a];

    FragU fz; fz.u[0]=0; fz.u[1]=0; fz.u[2]=0; fz.u[3]=0;
    fz.u[4]=0; fz.u[5]=0; fz.u[6]=0; fz.u[7]=0;

    for (int t = 0; t < 32; ++t) {
        // x-gates for this step (consumed last -> latency hidden)
        float xgv[3][4][4];
        if (lane < 16) {
            int idv[4];
#pragma unroll
            for (int i = 0; i < 4; ++i)
                idv[i] = (t == 0) ? 1 : tgt_ids[(brow0 + i) * 32 + (t - 1)];
#pragma unroll
            for (int g = 0; g < 3; ++g)
#pragma unroll
                for (int tl = 0; tl < 4; ++tl)
#pragma unroll
                    for (int i = 0; i < 4; ++i)
                        xgv[g][tl][i] = xpvd[idv[i] * 192 + g * 64 + tl * 16 + lane];
        }

        // h A-frags (rows 0..3 real, rest zero)
        bf16x8 ahh[2], ahl[2];
#pragma unroll
        for (int kf = 0; kf < 2; ++kf) {
            bf16x8 th = load_afrag(&hqp[w][0][ln & 3][kf * 32 + q * 8]);
            bf16x8 tlo = load_afrag(&hqp[w][1][ln & 3][kf * 32 + q * 8]);
            ahh[kf] = (ln < 4) ? th : fz.v;
            ahl[kf] = (ln < 4) ? tlo : fz.v;
        }

        // dproj: 4 col-tiles x 6 MFMA, weights from LDS
        f32x4 dacc[4];
#pragma unroll
        for (int tl = 0; tl < 4; ++tl) {
            f32x4 a = {0.f, 0.f, 0.f, 0.f};
#pragma unroll
            for (int kf = 0; kf < 2; ++kf) {
                FragU wh, wo;
                wh.q = *(const u32x4*)&wlds[(tl * 2 + kf) * 512 + lane * 8];
                wo.q = *(const u32x4*)&wlds[4096 + (tl * 2 + kf) * 512 + lane * 8];
                a = mfma16(ahl[kf], wh.v, a);
                a = mfma16(ahh[kf], wo.v, a);
                a = mfma16(ahh[kf], wh.v, a);
            }
            dacc[tl] = a;
        }
        if (lane < 16) {
#pragma unroll
            for (int tl = 0; tl < 4; ++tl)
#pragma unroll
                for (int i = 0; i < 4; ++i)
                    dpl_l[w][i][tl * 16 + lane] = (dacc[tl][i] + bdv[tl]) * 2.0f;
        }

        // scores + softmax (lane handles rows rp*2, rp*2+1 at s = lane&31)
        {
            const int sp = lane & 31, rp = lane >> 5;
#pragma unroll
            for (int k = 0; k < 2; ++k) {
                const int r = rp * 2 + k;
                const u16* ep = &encpT[((size_t)(brow0 + r) * 64) * 32 + sp];
                const float* dp = &dpl_l[w][r][0];
                float a0 = 0.f, a1 = 0.f, a2 = 0.f, a3 = 0.f;
#pragma unroll
                for (int a4 = 0; a4 < 16; ++a4) {
                    float e0 = __expf(dp[a4 * 4 + 0] + b2f(ep[(a4 * 4 + 0) * 32]));
                    float e1 = __expf(dp[a4 * 4 + 1] + b2f(ep[(a4 * 4 + 1) * 32]));
                    float e2_ = __expf(dp[a4 * 4 + 2] + b2f(ep[(a4 * 4 + 2) * 32]));
                    float e3 = __expf(dp[a4 * 4 + 3] + b2f(ep[(a4 * 4 + 3) * 32]));
                    a0 += vl[a4 * 4 + 0] * rcp_(e0 + 1.0f);
                    a1 += vl[a4 * 4 + 1] * rcp_(e1 + 1.0f);
                    a2 += vl[a4 * 4 + 2] * rcp_(e2_ + 1.0f);
                    a3 += vl[a4 * 4 + 3] * rcp_(e3 + 1.0f);
                }
                float logit = SVB - 2.0f * ((a0 + a1) + (a2 + a3));
                float m = logit;
#pragma unroll
                for (int off = 16; off > 0; off >>= 1)
                    m = fmaxf(m, __shfl_xor(m, off, 32));
                float e2 = __expf(logit - m);
                float ssum = e2;
#pragma unroll
                for (int off = 16; off > 0; off >>= 1)
                    ssum += __shfl_xor(ssum, off, 32);
                wl_l[w][r][sp] = e2 * rcp_(ssum);
            }
        }

        // ctx (lane handles rows rp*2, rp*2+1 at j-pair = 2*(lane&31))
        {
            const int j2 = lane & 31, rp = lane >> 5;
#pragma unroll
            for (int k = 0; k < 2; ++k) {
                const int r = rp * 2 + k;
                float c0 = 0.f, c1 = 0.f;
                const float* eb = &encF[((size_t)(brow0 + r) * 32) * 64 + 2 * j2];
#pragma unroll 8
                for (int s = 0; s < 32; ++s) {
                    float ww = wl_l[w][r][s];
                    f32x2 ev = *(const f32x2*)(eb + s * 64);
                    c0 += ww * ev[0]; c1 += ww * ev[1];
                }
                u16 h0_, l0_, h1_, l1_;
                split2(c0, h0_, l0_); split2(c1, h1_, l1_);
                cxp[w][0][r][2 * j2] = h0_; cxp[w][0][r][2 * j2 + 1] = h1_;
                cxp[w][1][r][2 * j2] = l0_; cxp[w][1][r][2 * j2 + 1] = l1_;
            }
        }

        // ctx A-frags
        bf16x8 achh[2], achl[2];
#pragma unroll
        for (int kf = 0; kf < 2; ++kf) {
            bf16x8 th = load_afrag(&cxp[w][0][ln & 3][kf * 32 + q * 8]);
            bf16x8 tlo = load_afrag(&cxp[w][1][ln & 3][kf * 32 + q * 8]);
            achh[kf] = (ln < 4) ? th : fz.v;
            achl[kf] = (ln < 4) ? tlo : fz.v;
        }

        // gates: all 192 cols for this wave's 4 rows
        f32x4 za[4], ra[4], nxa[4], nha[4];
#pragma unroll
        for (int g = 0; g < 3; ++g)
#pragma unroll
            for (int tl = 0; tl < 4; ++tl) {
                const int ct = g * 4 + tl;
                f32x4 a = {0.f, 0.f, 0.f, 0.f};
#pragma unroll
                for (int kf = 0; kf < 2; ++kf) {
                    FragU ch, cl;
                    ch.q = *(const u32x4*)&wlds[32768 + (ct * 2 + kf) * 512 + lane * 8];
                    cl.q = *(const u32x4*)&wlds[45056 + (ct * 2 + kf) * 512 + lane * 8];
                    a = mfma16(achl[kf], ch.v, a);
                    a = mfma16(achh[kf], cl.v, a);
                    a = mfma16(achh[kf], ch.v, a);
                }
                if (g < 2) {
#pragma unroll
                    for (int kf = 0; kf < 2; ++kf) {
                        FragU uh, ul;
                        uh.q = *(const u32x4*)&wlds[8192  + (ct * 2 + kf) * 512 + lane * 8];
                        ul.q = *(const u32x4*)&wlds[20480 + (ct * 2 + kf) * 512 + lane * 8];
                        a = mfma16(ahl[kf], uh.v, a);
                        a = mfma16(ahh[kf], ul.v, a);
                        a = mfma16(ahh[kf], uh.v, a);
                    }
                    if (g == 0) za[tl] = a; else ra[tl] = a;
                } else {
                    nxa[tl] = a;
                    f32x4 h2 = {0.f, 0.f, 0.f, 0.f};
#pragma unroll
                    for (int kf = 0; kf < 2; ++kf) {
                        FragU uh, ul;
                        uh.q = *(const u32x4*)&wlds[8192  + (ct * 2 + kf) * 512 + lane * 8];
                        ul.q = *(const u32x4*)&wlds[20480 + (ct * 2 + kf) * 512 + lane * 8];
                        h2 = mfma16(ahl[kf], uh.v, h2);
                        h2 = mfma16(ahh[kf], ul.v, h2);
                        h2 = mfma16(ahh[kf], uh.v, h2);
                    }
                    nha[tl] = h2;
                }
            }

        // combine + state update + output (lanes<16 own everything)
        if (lane < 16) {
#pragma unroll
            for (int tl = 0; tl < 4; ++tl)
#pragma unroll
                for (int i = 0; i < 4; ++i) {
                    float zz = sigm_(xgv[0][tl][i] + za[tl][i] + b13[0][tl]);
                    float rv = sigm_(xgv[1][tl][i] + ra[tl][i] + b13[1][tl]);
                    float nn = tanh_(xgv[2][tl][i] + nxa[tl][i]
                                     + rv * (nha[tl][i] + b13[2][tl]));
                    float nh = zz * hp[tl][i] + (1.0f - zz) * nn;
                    hp[tl][i] = nh;
                    int col = tl * 16 + lane;
                    size_t gidx = ((size_t)(brow0 + i) * 32 + t) * 64 + col;
                    u16 hi, lo; split2(nh, hi, lo);
                    hid_hi[gidx] = hi; hid_lo[gidx] = lo;
                    hqp[w][0][i][col] = hi; hqp[w][1][i][col] = lo;
                }
        }
        // no barrier: next step's hqp reads are same-wave, program-ordered
    }
}

// ---------------------------------------------------------------------------
extern "C" void kernel_launch(void* const* d_in, const int* in_sizes, int n_in,
                              void* d_out, int out_size, void* d_ws, size_t ws_size,
                              hipStream_t stream) {
    const int*   src_ids = (const int*)d_in[0];
    const int*   tgt_ids = (const int*)d_in[1];
    const float* src_emb = (const float*)d_in[2];
    const float* enc_Wf  = (const float*)d_in[3];
    const float* enc_Uf  = (const float*)d_in[4];
    const float* enc_bf  = (const float*)d_in[5];
    const float* enc_Wb  = (const float*)d_in[6];
    const float* enc_Ub  = (const float*)d_in[7];
    const float* enc_bb  = (const float*)d_in[8];
    const float* attn_We = (const float*)d_in[9];
    const float* attn_be = (const float*)d_in[10];
    const float* attn_Wd = (const float*)d_in[11];
    const float* attn_bd = (const float*)d_in[12];
    const float* attn_v  = (const float*)d_in[13];
    const float* attn_bv = (const float*)d_in[14];
    const float* dec_W   = (const float*)d_in[15];
    const float* dec_U   = (const float*)d_in[16];
    const float* dec_b   = (const float*)d_in[17];
    const float* out_W   = (const float*)d_in[18];
    const float* out_b   = (const float*)d_in[19];

    // ws layout (u16 units): encF fp32 [0,32 MiB), encpT bf16 [32,48),
    // hid_hi [48,64), hid_lo [64,80), xpv_f/b/d after. Peak ~80.6 MiB.
    u16* ws = (u16*)d_ws;
    float* encF  = (float*)ws;            // 16777216 u16 = 32 MiB
    u16* encpT   = ws + 16777216;
    u16* hid_hi  = ws + 25165824;
    u16* hid_lo  = ws + 33554432;
    float* xpv_f = (float*)(ws + 41943040);
    float* xpv_b = (float*)(ws + 42041344);
    float* xpvd  = (float*)(ws + 42139648);

    dim3 blk(256);
    hipMemsetAsync(encF, 0, 33554432, stream);   // zero encF (32 MiB)
    xpv_all<<<12, blk, 0, stream>>>(src_emb, enc_Wf, enc_bf, xpv_f,
                                    enc_Wb, enc_bb, xpv_b,
                                    out_W, dec_W, dec_b, xpvd);
    enc8<<<1024, blk, 0, stream>>>(src_ids, xpv_f, xpv_b, enc_Uf, enc_bf,
                                   enc_Ub, enc_bb, encF);
    gemm_hl<2, 64, 64><<<2048, blk, 0, stream>>>(
        encF, nullptr, nullptr, attn_We, attn_be, nullptr, encpT);
    dec_kernel<<<256, blk, 0, stream>>>(tgt_ids, xpvd, encF, encpT,
                                        dec_U, dec_W, dec_b,
                                        attn_Wd, attn_bd, attn_v, attn_bv,
                                        hid_hi, hid_lo);
    gemm_hl<3, 64, 256><<<2048, blk, 0, stream>>>(
        nullptr, hid_hi, hid_lo, out_W, out_b, (float*)d_out, nullptr);
}